// Round 1
// baseline (72.444 us; speedup 1.0000x reference)
//
#include <hip/hip_runtime.h>

// SymmetricPooling: depthwise 5x5 binary-symmetric conv, VALID, stride 1.
// x: (16,128,128,32) f32  ->  out: (16,124,124,288) f32, channel order c*9+f,
// f = eta*3 + phi, taps = {eta,4-eta} x {phi,4-phi} (deduped at centre).

#define BB 16
#define HH 128
#define WW 128
#define CC 32
#define OH 124
#define OW 124
#define NF 9
#define OC (CC * NF)   // 288
#define TX 4           // x positions per block
#define NXB (OW / TX)  // 31

__global__ __launch_bounds__(128)
void sympool_kernel(const float* __restrict__ x, float* __restrict__ out) {
    __shared__ float tile[TX * OC];  // 1152 floats = 4.5 KB

    const int t = threadIdx.x;
    const int c = t & 31;        // channel
    const int d = t >> 5;        // 0..3, x offset within tile

    const int blk  = blockIdx.x;
    const int xb   = blk % NXB;
    const int rest = blk / NXB;
    const int y    = rest % OH;
    const int b    = rest / OH;
    const int x0   = xb * TX;
    const int xx   = x0 + d;

    // Load the 5x5 input patch for (b, y..y+4, xx..xx+4, c).
    // Lanes 0..31 = channels (contiguous 128B), lanes 32..63 = next x -> 256B
    // coalesced per load instruction.
    const float* p = x + ((size_t)((b * HH + y) * WW + xx)) * CC + c;
    float v[5][5];
#pragma unroll
    for (int i = 0; i < 5; ++i) {
#pragma unroll
        for (int j = 0; j < 5; ++j) {
            v[i][j] = p[(i * WW + j) * CC];
        }
    }

    // Row sums: R[eta][j] = sum over i in {eta, 4-eta} (dedup) of v[i][j]
    float R[3][5];
#pragma unroll
    for (int j = 0; j < 5; ++j) {
        R[0][j] = v[0][j] + v[4][j];
        R[1][j] = v[1][j] + v[3][j];
        R[2][j] = v[2][j];
    }

    // Column sums -> 9 outputs, f = eta*3 + phi
    float* dst = &tile[d * OC + c * NF];
#pragma unroll
    for (int e = 0; e < 3; ++e) {
        dst[e * 3 + 0] = R[e][0] + R[e][4];
        dst[e * 3 + 1] = R[e][1] + R[e][3];
        dst[e * 3 + 2] = R[e][2];
    }

    __syncthreads();

    // Stream the 4x288-float tile to global as aligned float4 (fully
    // coalesced, whole cache lines -> no partial-line RMW on the write path).
    float4* outv = (float4*)(out + ((size_t)((b * OH + y) * OW + x0)) * OC);
    const float4* tv = (const float4*)tile;
    const int nvec = TX * OC / 4;  // 288
#pragma unroll
    for (int k = 0; k < 3; ++k) {
        int idx = t + k * 128;
        if (idx < nvec) outv[idx] = tv[idx];
    }
}

extern "C" void kernel_launch(void* const* d_in, const int* in_sizes, int n_in,
                              void* d_out, int out_size, void* d_ws, size_t ws_size,
                              hipStream_t stream) {
    const float* x = (const float*)d_in[0];
    // d_in[1] is the binary symmetric kernel; its structure is hardcoded.
    float* out = (float*)d_out;

    const int grid = BB * OH * NXB;  // 16*124*31 = 61504
    sympool_kernel<<<grid, 128, 0, stream>>>(x, out);
}